// Round 2
// baseline (1438.079 us; speedup 1.0000x reference)
//
#include <hip/hip_runtime.h>
#include <hip/hip_bf16.h>

// FourierKAN as fused GEMM: M=8192 (batch), N=1024 (outdim), K=16384 = 1024 i * 8 g * 2 (cos/sin)
// kk ordering: kk = i*16 + g*2 + t  (t=0 cos, t=1 sin), freq = g+1
// A[b][kk] = trig(x[b,i]*(g+1)) computed on the fly (bf16)
// B[j][kk] = fouriercoeffs[t][j][i][g] converted fp32->bf16 on the fly (reg-staged)

typedef __attribute__((ext_vector_type(8))) short short8;
typedef __attribute__((ext_vector_type(4))) float f32x4;

static __device__ __forceinline__ unsigned short f2bf(float f) {
  // round-to-nearest-even fp32 -> bf16 (finite inputs only)
  unsigned u = __builtin_bit_cast(unsigned, f);
  u += 0x7fffu + ((u >> 16) & 1u);
  return (unsigned short)(u >> 16);
}

__global__ __launch_bounds__(256, 2) void fkan_kernel(
    const float* __restrict__ X,   // [8192][1024]
    const float* __restrict__ W,   // [2][1024][1024][8]
    float* __restrict__ Y) {       // [8192][1024]
  constexpr int IN = 1024, N = 1024;
  constexpr int BM = 128, BN = 128, KT = 256;  // BK=64, K=16384

  __shared__ alignas(16) unsigned short Asb[BM * 64];  // [row][kk_local], 16 KB
  __shared__ alignas(16) unsigned short Bsb[BN * 64];  // [col][kk_local], 16 KB

  const int tid = threadIdx.x;
  const int bm = blockIdx.x & 63;   // M panel (64 of them)
  const int bn = blockIdx.x >> 6;   // N panel (8 of them)
  const int lane = tid & 63;
  const int w = tid >> 6;
  const int wm = w >> 1, wn = w & 1;  // 2x2 wave grid, 64x64 per wave

  const float* W0 = W;
  const float* W1 = W + 8388608;  // 1024*1024*8

  f32x4 acc[4][4];
#pragma unroll
  for (int m = 0; m < 4; ++m)
#pragma unroll
    for (int n = 0; n < 4; ++n) acc[m][n] = f32x4{0.f, 0.f, 0.f, 0.f};

  for (int kt = 0; kt < KT; ++kt) {
    const int ib = kt * 4;  // 4 input-dims per K-step (4*16 = 64 kk)
    __syncthreads();        // previous iteration's frag reads done

    // ---- stage B: fp32 W -> bf16 interleaved [col][kk]; 1024 chunks of 16B
#pragma unroll
    for (int p = 0; p < 4; ++p) {
      const int c = p * 256 + tid;
      const int nl = c >> 3;            // col within tile
      const int il = (c & 7) >> 1;      // which of 4 i's
      const int gh = (c & 1) * 4;       // g base (0 or 4)
      const size_t base = (size_t)(bn * BN + nl) * 8192 + (size_t)(ib + il) * 8 + gh;
      const float4 w0 = *(const float4*)(W0 + base);
      const float4 w1 = *(const float4*)(W1 + base);
      short8 v;
      v[0] = (short)f2bf(w0.x); v[1] = (short)f2bf(w1.x);
      v[2] = (short)f2bf(w0.y); v[3] = (short)f2bf(w1.y);
      v[4] = (short)f2bf(w0.z); v[5] = (short)f2bf(w1.z);
      v[6] = (short)f2bf(w0.w); v[7] = (short)f2bf(w1.w);
      *(short8*)(Bsb + c * 8) = v;  // lane-contiguous 16B -> conflict-free ds_write_b128
    }

    // ---- stage A: trig; 1024 chunks of 16B (row, i, half-of-g-range)
#pragma unroll
    for (int p = 0; p < 4; ++p) {
      const int c = p * 256 + tid;
      const int row = c >> 3;
      const int il = (c & 7) >> 1;
      const int half = c & 1;  // g 0..3 or 4..7
      const float xv = X[(size_t)(bm * BM + row) * IN + ib + il];
      float s1, c1;
      __sincosf(xv, &s1, &c1);
      float ca, sa;
      if (half == 0) {
        ca = c1; sa = s1;  // freq 1
      } else {
        // freq 5 via two doublings + one addition step
        const float c2 = c1 * c1 - s1 * s1, s2 = 2.f * s1 * c1;
        const float c4 = c2 * c2 - s2 * s2, s4 = 2.f * s2 * c2;
        ca = c4 * c1 - s4 * s1; sa = s4 * c1 + c4 * s1;
      }
      const float cb = ca * c1 - sa * s1, sb = sa * c1 + ca * s1;
      const float cc = cb * c1 - sb * s1, sc = sb * c1 + cb * s1;
      const float cd = cc * c1 - sc * s1, sd = sc * c1 + cc * s1;
      short8 v;
      v[0] = (short)f2bf(ca); v[1] = (short)f2bf(sa);
      v[2] = (short)f2bf(cb); v[3] = (short)f2bf(sb);
      v[4] = (short)f2bf(cc); v[5] = (short)f2bf(sc);
      v[6] = (short)f2bf(cd); v[7] = (short)f2bf(sd);
      *(short8*)(Asb + c * 8) = v;
    }

    __syncthreads();

    // ---- fragment loads + MFMA (m97 pattern; layouts HW-verified m89/m91)
    short8 af[2][4], bf_[2][4];
#pragma unroll
    for (int ks = 0; ks < 2; ++ks) {
#pragma unroll
      for (int m = 0; m < 4; ++m)
        af[ks][m] = *(const short8*)(Asb + (wm * 64 + m * 16 + (lane & 15)) * 64 +
                                     ks * 32 + (lane >> 4) * 8);
#pragma unroll
      for (int n = 0; n < 4; ++n)
        bf_[ks][n] = *(const short8*)(Bsb + (wn * 64 + n * 16 + (lane & 15)) * 64 +
                                      ks * 32 + (lane >> 4) * 8);
    }
#pragma unroll
    for (int ks = 0; ks < 2; ++ks)
#pragma unroll
      for (int m = 0; m < 4; ++m)
#pragma unroll
        for (int n = 0; n < 4; ++n)
          acc[m][n] = __builtin_amdgcn_mfma_f32_16x16x32_bf16(
              af[ks][m], bf_[ks][n], acc[m][n], 0, 0, 0);
  }

  // ---- epilogue: C/D layout col=lane&15, row=(lane>>4)*4+r
#pragma unroll
  for (int m = 0; m < 4; ++m) {
    const int r0 = bm * BM + wm * 64 + m * 16 + (lane >> 4) * 4;
#pragma unroll
    for (int n = 0; n < 4; ++n) {
      const int col = bn * BN + wn * 64 + n * 16 + (lane & 15);
#pragma unroll
      for (int r = 0; r < 4; ++r)
        Y[(size_t)(r0 + r) * N + col] = acc[m][n][r];
    }
  }
}

extern "C" void kernel_launch(void* const* d_in, const int* in_sizes, int n_in,
                              void* d_out, int out_size, void* d_ws, size_t ws_size,
                              hipStream_t stream) {
  const float* x = (const float*)d_in[0];
  const float* w = (const float*)d_in[1];
  float* y = (float*)d_out;
  fkan_kernel<<<dim3(512), dim3(256), 0, stream>>>(x, w, y);
}

// Round 5
// 647.981 us; speedup vs baseline: 2.2193x; 2.2193x over previous
//
#include <hip/hip_runtime.h>

// FourierKAN as fused GEMM: M=8192, N=1024, K=16384 = 1024 i * 8 g * 2 (cos/sin)
// kk = i*16 + g*2 + t (t=0 cos, t=1 sin), freq = g+1.
// Base: round-2 kernel (verified pass, absmax 0.031). Deltas, each isolated-safe:
//   (1) register prefetch pipeline for X/W (pure load reordering)
//   (2) T2 XOR swizzle on LDS write+read (same involution both sides)

typedef __attribute__((ext_vector_type(8))) short short8;
typedef __attribute__((ext_vector_type(4))) float f32x4;

static __device__ __forceinline__ unsigned short f2bf(float f) {
  // round-to-nearest-even fp32 -> bf16 (finite inputs only)
  unsigned u = __builtin_bit_cast(unsigned, f);
  u += 0x7fffu + ((u >> 16) & 1u);
  return (unsigned short)(u >> 16);
}

static __device__ __forceinline__ short8 trig_pack(float xv, int half) {
  float s1, c1;
  __sincosf(xv, &s1, &c1);
  float ca, sa;
  if (half == 0) {
    ca = c1; sa = s1;  // freq 1
  } else {
    // freq 5 via two doublings + one addition step
    const float c2 = c1 * c1 - s1 * s1, s2 = 2.f * s1 * c1;
    const float c4 = c2 * c2 - s2 * s2, s4 = 2.f * s2 * c2;
    ca = c4 * c1 - s4 * s1; sa = s4 * c1 + c4 * s1;
  }
  const float cb = ca * c1 - sa * s1, sb = sa * c1 + ca * s1;
  const float cc = cb * c1 - sb * s1, sc = sb * c1 + cb * s1;
  const float cd = cc * c1 - sc * s1, sd = sc * c1 + cc * s1;
  short8 v;
  v[0] = (short)f2bf(ca); v[1] = (short)f2bf(sa);
  v[2] = (short)f2bf(cb); v[3] = (short)f2bf(sb);
  v[4] = (short)f2bf(cc); v[5] = (short)f2bf(sc);
  v[6] = (short)f2bf(cd); v[7] = (short)f2bf(sd);
  return v;
}

static __device__ __forceinline__ short8 pack_w(float4 w0, float4 w1) {
  short8 v;
  v[0] = (short)f2bf(w0.x); v[1] = (short)f2bf(w1.x);
  v[2] = (short)f2bf(w0.y); v[3] = (short)f2bf(w1.y);
  v[4] = (short)f2bf(w0.z); v[5] = (short)f2bf(w1.z);
  v[6] = (short)f2bf(w0.w); v[7] = (short)f2bf(w1.w);
  return v;
}

__global__ __launch_bounds__(256, 2) void fkan_kernel(
    const float* __restrict__ X,   // [8192][1024]
    const float* __restrict__ W,   // [2][1024][1024][8]
    float* __restrict__ Y) {       // [8192][1024]
  constexpr int N = 1024, KT = 256;

  __shared__ alignas(16) unsigned short Asb[128 * 64];  // [row][kk], swizzled, 16 KB
  __shared__ alignas(16) unsigned short Bsb[128 * 64];  // [col][kk], swizzled, 16 KB

  const int tid = threadIdx.x;
  const int bm = blockIdx.x & 63;   // round-2 mapping kept verbatim
  const int bn = blockIdx.x >> 6;
  const int lane = tid & 63;
  const int w = tid >> 6;
  const int wm = w >> 1, wn = w & 1;  // 2x2 wave grid, 64x64 per wave

  const float* W0 = W;
  const float* W1 = W + 8388608;  // 1024*1024*8

  // staging roles (round-2: chunk p handles c = p*256 + tid)
  // row/col = p*32 + rowbase, il = (tid&7)>>1, half = tid&1, gh = half*4
  const int rowbase = tid >> 3;          // 0..31
  const int il = (tid & 7) >> 1;         // 0..3
  const int half = tid & 1;
  const int sst = (rowbase & 7) << 3;    // store-side swizzle (row&7 == rowbase&7)
  const int aoff0 = rowbase * 64 + ((il * 16 + half * 8) ^ sst);  // + p*2048
  const size_t xaddr0 = (size_t)(bm * 128 + rowbase) * 1024 + il;          // + kt*4 + p*32768
  const size_t wbase0 = (size_t)(bn * 128 + rowbase) * 8192 + il * 8 + half * 4;  // + kt*32 + p*262144

  f32x4 acc[4][4];
#pragma unroll
  for (int m = 0; m < 4; ++m)
#pragma unroll
    for (int n = 0; n < 4; ++n) acc[m][n] = f32x4{0.f, 0.f, 0.f, 0.f};

  // ---- prologue: load kt=0 inputs into registers
  float xq[4];
  float4 wq0[4], wq1[4];
#pragma unroll
  for (int p = 0; p < 4; ++p) {
    xq[p] = X[xaddr0 + p * 32768];
    wq0[p] = *(const float4*)(W0 + wbase0 + p * 262144);
    wq1[p] = *(const float4*)(W1 + wbase0 + p * 262144);
  }

  for (int kt = 0; kt < KT; ++kt) {
    // ---- convert this step's registers to bf16 tiles
    short8 va[4], vb[4];
#pragma unroll
    for (int p = 0; p < 4; ++p) {
      va[p] = trig_pack(xq[p], half);
      vb[p] = pack_w(wq0[p], wq1[p]);
    }

    __syncthreads();  // previous iteration's frag reads done
#pragma unroll
    for (int p = 0; p < 4; ++p) {
      *(short8*)(Asb + aoff0 + p * 2048) = va[p];
      *(short8*)(Bsb + aoff0 + p * 2048) = vb[p];  // same offset formula for B
    }

    // ---- prefetch kt+1 (in flight across barrier + MFMA phase)
    const int ktn = (kt < KT - 1) ? kt + 1 : kt;
    const size_t xo = xaddr0 + (size_t)ktn * 4;
    const size_t wo = wbase0 + (size_t)ktn * 32;
#pragma unroll
    for (int p = 0; p < 4; ++p) {
      xq[p] = X[xo + p * 32768];
      wq0[p] = *(const float4*)(W0 + wo + p * 262144);
      wq1[p] = *(const float4*)(W1 + wo + p * 262144);
    }

    __syncthreads();  // tiles visible

    // ---- fragment loads (swizzled read: same involution) + MFMA
    const int sr = (lane & 7) << 3;  // row&7 == lane&7 for all frag rows/cols
    short8 af[2][4], bf_[2][4];
#pragma unroll
    for (int ks = 0; ks < 2; ++ks) {
      const int koff = ks * 32 + (lane >> 4) * 8;
#pragma unroll
      for (int m = 0; m < 4; ++m)
        af[ks][m] = *(const short8*)(Asb + (wm * 64 + m * 16 + (lane & 15)) * 64 +
                                     (koff ^ sr));
#pragma unroll
      for (int n = 0; n < 4; ++n)
        bf_[ks][n] = *(const short8*)(Bsb + (wn * 64 + n * 16 + (lane & 15)) * 64 +
                                      (koff ^ sr));
    }
#pragma unroll
    for (int ks = 0; ks < 2; ++ks)
#pragma unroll
      for (int m = 0; m < 4; ++m)
#pragma unroll
        for (int n = 0; n < 4; ++n)
          acc[m][n] = __builtin_amdgcn_mfma_f32_16x16x32_bf16(
              af[ks][m], bf_[ks][n], acc[m][n], 0, 0, 0);
  }

  // ---- epilogue: C/D layout col=lane&15, row=(lane>>4)*4+r (m89/m91-verified)
#pragma unroll
  for (int m = 0; m < 4; ++m) {
    const int r0 = bm * 128 + wm * 64 + m * 16 + (lane >> 4) * 4;
#pragma unroll
    for (int n = 0; n < 4; ++n) {
      const int col = bn * 128 + wn * 64 + n * 16 + (lane & 15);
#pragma unroll
      for (int r = 0; r < 4; ++r)
        Y[(size_t)(r0 + r) * N + col] = acc[m][n][r];
    }
  }
}

extern "C" void kernel_launch(void* const* d_in, const int* in_sizes, int n_in,
                              void* d_out, int out_size, void* d_ws, size_t ws_size,
                              hipStream_t stream) {
  const float* x = (const float*)d_in[0];
  const float* w = (const float*)d_in[1];
  float* y = (float*)d_out;
  fkan_kernel<<<dim3(512), dim3(256), 0, stream>>>(x, w, y);
}

// Round 7
// 469.762 us; speedup vs baseline: 3.0613x; 1.3794x over previous
//
#include <hip/hip_runtime.h>

// FourierKAN fused GEMM, round 6.
// M=8192, N=1024, K=16384 (kk = i*16 + g*2 + t; t=0 cos, t=1 sin; freq g+1).
// Path A (ws >= 96MB): pre-pass sincos (A2) + bf16 W (Bq) into d_ws; main kernel
//   stages B via global_load_lds (pre-swizzled per-lane source, linear LDS dest),
//   A via Chebyshev recurrence from (cos x, sin x); both tiles double-buffered,
//   ONE barrier per K-step. MFMA core + swizzle identical to round-5 (verified).
// Path B: round-5 kernel verbatim (fallback).

typedef __attribute__((ext_vector_type(8))) short short8;
typedef __attribute__((ext_vector_type(4))) float f32x4;
typedef __attribute__((ext_vector_type(4))) unsigned int u32x4;

static __device__ __forceinline__ unsigned short f2bf(float f) {
  unsigned u = __builtin_bit_cast(unsigned, f);
  u += 0x7fffu + ((u >> 16) & 1u);
  return (unsigned short)(u >> 16);
}
static __device__ __forceinline__ unsigned int packbf2(float lo, float hi) {
  return (unsigned)f2bf(lo) | ((unsigned)f2bf(hi) << 16);
}

// ---------------- pre-pass A: A2[kt][row][il][2] = (cos x, sin x) ----------------
__global__ __launch_bounds__(256) void fkan_pre_a(const float* __restrict__ X,
                                                  float* __restrict__ A2) {
  const unsigned t = blockIdx.x * 256 + threadIdx.x;  // t = (kt*8192+row)*4+il
  const unsigned il = t & 3, row = (t >> 2) & 8191, kt = t >> 15;
  const float x = X[row * 1024 + kt * 4 + il];
  float s, c;
  __sincosf(x, &s, &c);
  *(float2*)(A2 + (size_t)t * 2) = make_float2(c, s);
}

// ---------------- pre-pass B: Bq[j][kk] bf16, kk interleaved ----------------
__global__ __launch_bounds__(256) void fkan_pre_b(const float* __restrict__ W,
                                                  unsigned short* __restrict__ Bq) {
  const unsigned t = blockIdx.x * 256 + threadIdx.x;  // t = j*1024 + i
  const unsigned i = t & 1023, j = t >> 10;
  const float* w0 = W + (size_t)j * 8192 + i * 8;
  const float* w1 = w0 + 8388608;
  const float4 a0 = *(const float4*)w0, a1 = *(const float4*)(w0 + 4);
  const float4 b0 = *(const float4*)w1, b1 = *(const float4*)(w1 + 4);
  u32x4* out = (u32x4*)(Bq + (size_t)t * 16);
  out[0] = u32x4{packbf2(a0.x, b0.x), packbf2(a0.y, b0.y),
                 packbf2(a0.z, b0.z), packbf2(a0.w, b0.w)};
  out[1] = u32x4{packbf2(a1.x, b1.x), packbf2(a1.y, b1.y),
                 packbf2(a1.z, b1.z), packbf2(a1.w, b1.w)};
}

// ---------------- main kernel ----------------
__global__ __launch_bounds__(256, 2) void fkan_main(
    const float* __restrict__ A2,           // [256][8192][4][2] f32
    const unsigned short* __restrict__ Bq,  // [1024][16384] bf16
    float* __restrict__ Y) {                // [8192][1024]
  constexpr int KT = 256;
  __shared__ alignas(16) unsigned short Asb[2][128 * 64];  // 32 KB
  __shared__ alignas(16) unsigned short Bsb[2][128 * 64];  // 32 KB

  const int tid = threadIdx.x;
  const int bn = blockIdx.x & 7, bm = blockIdx.x >> 3;  // XCD-pinned bn panel
  const int lane = tid & 63;
  const int w = tid >> 6;
  const int wm = w >> 1, wn = w & 1;  // 2x2 waves, 64x64 each

  // A roles: thread handles (row0, il) and (row1=row0+64, il)
  const int il = tid & 3;
  const int row0 = tid >> 2, row1 = row0 + 64;
  const int e0 = (il * 16) ^ ((row0 & 7) << 3);  // row1&7 == row0&7
  const float* a2p0 = A2 + ((size_t)(bm * 128 + row0) * 4 + il) * 2;
  const float* a2p1 = A2 + ((size_t)(bm * 128 + row1) * 4 + il) * 2;

  // B roles: 4 global_load_lds per wave; per-lane pre-swizzled source
  const int l3 = lane >> 3, l7 = lane & 7;
  const unsigned short* bsrc[4];
#pragma unroll
  for (int j = 0; j < 4; ++j) {
    const int col_l = w * 32 + j * 8 + l3;          // col_l&7 == l3
    bsrc[j] = Bq + (size_t)(bn * 128 + col_l) * 16384 + (l7 ^ l3) * 8;
  }

  auto issueB = [&](int kt, int buf) {
#pragma unroll
    for (int j = 0; j < 4; ++j) {
      const unsigned short* src = bsrc[j] + kt * 64;
      unsigned short* dst = &Bsb[buf][(w * 32 + j * 8) * 64];
      __builtin_amdgcn_global_load_lds(
          (const __attribute__((address_space(1))) unsigned int*)src,
          (__attribute__((address_space(3))) unsigned int*)dst, 16, 0, 0);
    }
  };
  auto chebpack = [&](float2 cs, unsigned* pk) {
    const float c1 = cs.x, s1 = cs.y, tc = 2.f * c1;
    float cp = c1, sp = s1;
    float cq = tc * c1 - 1.f, sq = tc * s1;
    pk[0] = packbf2(c1, s1);
    pk[1] = packbf2(cq, sq);
#pragma unroll
    for (int g = 2; g < 8; ++g) {
      const float cn = tc * cq - cp, sn = tc * sq - sp;
      pk[g] = packbf2(cn, sn);
      cp = cq; sp = sq; cq = cn; sq = sn;
    }
  };
  auto writeA = [&](int buf, const unsigned* k0, const unsigned* k1) {
    *(u32x4*)(&Asb[buf][row0 * 64 + e0]) = u32x4{k0[0], k0[1], k0[2], k0[3]};
    *(u32x4*)(&Asb[buf][row0 * 64 + (e0 ^ 8)]) = u32x4{k0[4], k0[5], k0[6], k0[7]};
    *(u32x4*)(&Asb[buf][row1 * 64 + e0]) = u32x4{k1[0], k1[1], k1[2], k1[3]};
    *(u32x4*)(&Asb[buf][row1 * 64 + (e0 ^ 8)]) = u32x4{k1[4], k1[5], k1[6], k1[7]};
  };

  f32x4 acc[4][4];
#pragma unroll
  for (int m = 0; m < 4; ++m)
#pragma unroll
    for (int n = 0; n < 4; ++n) acc[m][n] = f32x4{0.f, 0.f, 0.f, 0.f};

  // prologue: stage kt=0, prefetch kt=1
  unsigned k0[8], k1[8];
  {
    chebpack(*(const float2*)a2p0, k0);
    chebpack(*(const float2*)a2p1, k1);
    writeA(0, k0, k1);
    issueB(0, 0);
  }
  float2 avA0 = *(const float2*)(a2p0 + 65536);
  float2 avA1 = *(const float2*)(a2p1 + 65536);
  __syncthreads();

  int buf = 0;
  for (int kt = 0; kt < KT; ++kt) {
    const int nb = buf ^ 1;
    if (kt + 1 < KT) issueB(kt + 1, nb);       // flies under MFMA phase
    float2 avB0 = avA0, avB1 = avA1;
    if (kt + 2 < KT) {                          // A' prefetch, also early
      avB0 = *(const float2*)(a2p0 + (size_t)(kt + 2) * 65536);
      avB1 = *(const float2*)(a2p1 + (size_t)(kt + 2) * 65536);
    }

    // ---- MFMA phase on buf (round-5 verified reads + layout)
    {
      const int sr = (lane & 7) << 3;
      short8 af[2][4], bf_[2][4];
#pragma unroll
      for (int ks = 0; ks < 2; ++ks) {
        const int koff = (ks * 32 + (lane >> 4) * 8) ^ sr;
#pragma unroll
        for (int m = 0; m < 4; ++m)
          af[ks][m] = *(const short8*)(&Asb[buf][(wm * 64 + m * 16 + (lane & 15)) * 64 + koff]);
#pragma unroll
        for (int n = 0; n < 4; ++n)
          bf_[ks][n] = *(const short8*)(&Bsb[buf][(wn * 64 + n * 16 + (lane & 15)) * 64 + koff]);
      }
#pragma unroll
      for (int ks = 0; ks < 2; ++ks)
#pragma unroll
        for (int m = 0; m < 4; ++m)
#pragma unroll
          for (int n = 0; n < 4; ++n)
            acc[m][n] = __builtin_amdgcn_mfma_f32_16x16x32_bf16(
                af[ks][m], bf_[ks][n], acc[m][n], 0, 0, 0);
    }

    if (kt + 1 < KT) {  // stage next A tile
      chebpack(avA0, k0);
      chebpack(avA1, k1);
      writeA(nb, k0, k1);
    }
    __syncthreads();  // drains gload_lds(kt+1) + A' prefetch + ds ops
    avA0 = avB0; avA1 = avB1;
    buf = nb;
  }

  // epilogue: C/D layout col=lane&15, row=(lane>>4)*4+r (m89/m91-verified)
#pragma unroll
  for (int m = 0; m < 4; ++m) {
    const int r0 = bm * 128 + wm * 64 + m * 16 + (lane >> 4) * 4;
#pragma unroll
    for (int n = 0; n < 4; ++n) {
      const int col = bn * 128 + wn * 64 + n * 16 + (lane & 15);
#pragma unroll
      for (int r = 0; r < 4; ++r)
        Y[(size_t)(r0 + r) * 1024 + col] = acc[m][n][r];
    }
  }
}

// ---------------- fallback: round-5 kernel verbatim ----------------
static __device__ __forceinline__ short8 trig_pack(float xv, int half) {
  float s1, c1;
  __sincosf(xv, &s1, &c1);
  float ca, sa;
  if (half == 0) {
    ca = c1; sa = s1;
  } else {
    const float c2 = c1 * c1 - s1 * s1, s2 = 2.f * s1 * c1;
    const float c4 = c2 * c2 - s2 * s2, s4 = 2.f * s2 * c2;
    ca = c4 * c1 - s4 * s1; sa = s4 * c1 + c4 * s1;
  }
  const float cb = ca * c1 - sa * s1, sb = sa * c1 + ca * s1;
  const float cc = cb * c1 - sb * s1, sc = sb * c1 + cb * s1;
  const float cd = cc * c1 - sc * s1, sd = sc * c1 + cc * s1;
  short8 v;
  v[0] = (short)f2bf(ca); v[1] = (short)f2bf(sa);
  v[2] = (short)f2bf(cb); v[3] = (short)f2bf(sb);
  v[4] = (short)f2bf(cc); v[5] = (short)f2bf(sc);
  v[6] = (short)f2bf(cd); v[7] = (short)f2bf(sd);
  return v;
}
static __device__ __forceinline__ short8 pack_w(float4 w0, float4 w1) {
  short8 v;
  v[0] = (short)f2bf(w0.x); v[1] = (short)f2bf(w1.x);
  v[2] = (short)f2bf(w0.y); v[3] = (short)f2bf(w1.y);
  v[4] = (short)f2bf(w0.z); v[5] = (short)f2bf(w1.z);
  v[6] = (short)f2bf(w0.w); v[7] = (short)f2bf(w1.w);
  return v;
}

__global__ __launch_bounds__(256, 2) void fkan_fallback(
    const float* __restrict__ X, const float* __restrict__ W,
    float* __restrict__ Y) {
  constexpr int N = 1024, KT = 256;
  __shared__ alignas(16) unsigned short Asb[128 * 64];
  __shared__ alignas(16) unsigned short Bsb[128 * 64];
  const int tid = threadIdx.x;
  const int bm = blockIdx.x & 63;
  const int bn = blockIdx.x >> 6;
  const int lane = tid & 63;
  const int w = tid >> 6;
  const int wm = w >> 1, wn = w & 1;
  const float* W0 = W;
  const float* W1 = W + 8388608;
  const int rowbase = tid >> 3;
  const int il = (tid & 7) >> 1;
  const int half = tid & 1;
  const int sst = (rowbase & 7) << 3;
  const int aoff0 = rowbase * 64 + ((il * 16 + half * 8) ^ sst);
  const size_t xaddr0 = (size_t)(bm * 128 + rowbase) * 1024 + il;
  const size_t wbase0 = (size_t)(bn * 128 + rowbase) * 8192 + il * 8 + half * 4;

  f32x4 acc[4][4];
#pragma unroll
  for (int m = 0; m < 4; ++m)
#pragma unroll
    for (int n = 0; n < 4; ++n) acc[m][n] = f32x4{0.f, 0.f, 0.f, 0.f};

  float xq[4];
  float4 wq0[4], wq1[4];
#pragma unroll
  for (int p = 0; p < 4; ++p) {
    xq[p] = X[xaddr0 + p * 32768];
    wq0[p] = *(const float4*)(W0 + wbase0 + p * 262144);
    wq1[p] = *(const float4*)(W1 + wbase0 + p * 262144);
  }

  for (int kt = 0; kt < KT; ++kt) {
    short8 va[4], vb[4];
#pragma unroll
    for (int p = 0; p < 4; ++p) {
      va[p] = trig_pack(xq[p], half);
      vb[p] = pack_w(wq0[p], wq1[p]);
    }
    __syncthreads();
#pragma unroll
    for (int p = 0; p < 4; ++p) {
      *(short8*)(Asb + aoff0 + p * 2048) = va[p];
      *(short8*)(Bsb + aoff0 + p * 2048) = vb[p];
    }
    const int ktn = (kt < KT - 1) ? kt + 1 : kt;
    const size_t xo = xaddr0 + (size_t)ktn * 4;
    const size_t wo = wbase0 + (size_t)ktn * 32;
#pragma unroll
    for (int p = 0; p < 4; ++p) {
      xq[p] = X[xo + p * 32768];
      wq0[p] = *(const float4*)(W0 + wo + p * 262144);
      wq1[p] = *(const float4*)(W1 + wo + p * 262144);
    }
    __syncthreads();
    const int sr = (lane & 7) << 3;
    short8 af[2][4], bf_[2][4];
#pragma unroll
    for (int ks = 0; ks < 2; ++ks) {
      const int koff = ks * 32 + (lane >> 4) * 8;
#pragma unroll
      for (int m = 0; m < 4; ++m)
        af[ks][m] = *(const short8*)(Asb + (wm * 64 + m * 16 + (lane & 15)) * 64 + (koff ^ sr));
#pragma unroll
      for (int n = 0; n < 4; ++n)
        bf_[ks][n] = *(const short8*)(Bsb + (wn * 64 + n * 16 + (lane & 15)) * 64 + (koff ^ sr));
    }
#pragma unroll
    for (int ks = 0; ks < 2; ++ks)
#pragma unroll
      for (int m = 0; m < 4; ++m)
#pragma unroll
        for (int n = 0; n < 4; ++n)
          acc[m][n] = __builtin_amdgcn_mfma_f32_16x16x32_bf16(
              af[ks][m], bf_[ks][n], acc[m][n], 0, 0, 0);
  }
#pragma unroll
  for (int m = 0; m < 4; ++m) {
    const int r0 = bm * 128 + wm * 64 + m * 16 + (lane >> 4) * 4;
#pragma unroll
    for (int n = 0; n < 4; ++n) {
      const int col = bn * 128 + wn * 64 + n * 16 + (lane & 15);
#pragma unroll
      for (int r = 0; r < 4; ++r)
        Y[(size_t)(r0 + r) * N + col] = acc[m][n][r];
    }
  }
}

extern "C" void kernel_launch(void* const* d_in, const int* in_sizes, int n_in,
                              void* d_out, int out_size, void* d_ws, size_t ws_size,
                              hipStream_t stream) {
  const float* x = (const float*)d_in[0];
  const float* w = (const float*)d_in[1];
  float* y = (float*)d_out;
  constexpr size_t A2_BYTES = 67108864ull;   // 64 MB sincos f32
  constexpr size_t BQ_BYTES = 33554432ull;   // 32 MB bf16 W
  if (ws_size >= A2_BYTES + BQ_BYTES) {
    float* a2 = (float*)d_ws;
    unsigned short* bq = (unsigned short*)((char*)d_ws + A2_BYTES);
    fkan_pre_a<<<dim3(32768), dim3(256), 0, stream>>>(x, a2);
    fkan_pre_b<<<dim3(4096), dim3(256), 0, stream>>>(w, bq);
    fkan_main<<<dim3(512), dim3(256), 0, stream>>>(a2, bq, y);
  } else {
    fkan_fallback<<<dim3(512), dim3(256), 0, stream>>>(x, w, y);
  }
}

// Round 8
// 467.545 us; speedup vs baseline: 3.0758x; 1.0047x over previous
//
#include <hip/hip_runtime.h>
#include <hip/hip_bf16.h>

// FourierKAN fused GEMM, round 8.
// M=8192, N=1024, K=16384 (kk = i*16 + g*2 + t; t=0 cos, t=1 sin; freq g+1).
// Path A (ws >= 96MB): pre-pass sincos A2[row][kt][il][2] + bf16 Bq[j][kk] in d_ws.
//   Main: 128x256 tile, 512 thr (8 waves 2x4), dbuf LDS, B via global_load_lds
//   (pre-swizzled source), A via Chebyshev from (cos x, sin x), cvt_pk packing.
// Path B: round-5 kernel verbatim (verified fallback).

typedef __attribute__((ext_vector_type(8))) short short8;
typedef __attribute__((ext_vector_type(4))) float f32x4;
typedef __attribute__((ext_vector_type(4))) unsigned int u32x4;

static __device__ __forceinline__ unsigned short f2bf_rne(float f) {
  unsigned u = __builtin_bit_cast(unsigned, f);
  u += 0x7fffu + ((u >> 16) & 1u);
  return (unsigned short)(u >> 16);
}
static __device__ __forceinline__ unsigned int packbf2(float lo, float hi) {
  // scalar casts -> compiler emits v_cvt_pk_bf16_f32 (m240)
  const unsigned short a = __builtin_bit_cast(unsigned short, __float2bfloat16(lo));
  const unsigned short b = __builtin_bit_cast(unsigned short, __float2bfloat16(hi));
  return (unsigned)a | ((unsigned)b << 16);
}

// ---- pre-pass A: A2[row][kt][il][2] = (cos x[row][kt*4+il], sin ...), coalesced both sides
__global__ __launch_bounds__(256) void fkan_pre_a(const float* __restrict__ X,
                                                  float* __restrict__ A2) {
  const int row = blockIdx.x;        // 8192 blocks
  const int k = threadIdx.x;         // kt = k, 256 threads
  const float4 xv = *(const float4*)(X + (size_t)row * 1024 + k * 4);
  float s0, c0, s1, c1, s2, c2, s3, c3;
  __sincosf(xv.x, &s0, &c0);
  __sincosf(xv.y, &s1, &c1);
  __sincosf(xv.z, &s2, &c2);
  __sincosf(xv.w, &s3, &c3);
  float* out = A2 + (size_t)row * 2048 + k * 8;
  *(f32x4*)out = f32x4{c0, s0, c1, s1};
  *(f32x4*)(out + 4) = f32x4{c2, s2, c3, s3};
}

// ---- pre-pass B: Bq[j][kk] bf16, kk interleaved
__global__ __launch_bounds__(256) void fkan_pre_b(const float* __restrict__ W,
                                                  unsigned short* __restrict__ Bq) {
  const unsigned t = blockIdx.x * 256 + threadIdx.x;  // t = j*1024 + i
  const float* w0 = W + (size_t)t * 8;
  const float* w1 = w0 + 8388608;
  const float4 a0 = *(const float4*)w0, a1 = *(const float4*)(w0 + 4);
  const float4 b0 = *(const float4*)w1, b1 = *(const float4*)(w1 + 4);
  u32x4* out = (u32x4*)(Bq + (size_t)t * 16);
  out[0] = u32x4{packbf2(a0.x, b0.x), packbf2(a0.y, b0.y),
                 packbf2(a0.z, b0.z), packbf2(a0.w, b0.w)};
  out[1] = u32x4{packbf2(a1.x, b1.x), packbf2(a1.y, b1.y),
                 packbf2(a1.z, b1.z), packbf2(a1.w, b1.w)};
}

// ---- main kernel: 128x256 tile, 512 threads
__global__ __launch_bounds__(512, 2) void fkan_main(
    const float* __restrict__ A2,           // [8192][256][4][2] f32
    const unsigned short* __restrict__ Bq,  // [1024][16384] bf16
    float* __restrict__ Y) {                // [8192][1024]
  constexpr int KT = 256;
  __shared__ alignas(16) unsigned short Asb[2][128 * 64];  // 32 KB
  __shared__ alignas(16) unsigned short Bsb[2][256 * 64];  // 64 KB

  const int tid = threadIdx.x;
  const int bnp = blockIdx.x & 3, bm = blockIdx.x >> 2;  // 4 N-panels x 64 M-panels
  const int lane = tid & 63;
  const int w = tid >> 6;                 // 0..7
  const int wm = w >> 2, wn = w & 3;      // 2x4 wave grid; wave tile 64x64

  // A role: one (row0, il) pair per thread
  const int il = tid & 3;
  const int row0 = tid >> 2;              // 0..127
  const int e0 = (il * 16) ^ ((row0 & 7) << 3);
  const float* a2p0 = A2 + (size_t)(bm * 128 + row0) * 2048 + il * 2;

  // B role: 4 global_load_lds per wave, pre-swizzled per-lane source
  const int l3 = lane >> 3, l7 = lane & 7;
  const unsigned short* bsrc[4];
#pragma unroll
  for (int j = 0; j < 4; ++j) {
    const int col_l = w * 32 + j * 8 + l3;  // 0..255, col_l&7 == l3
    bsrc[j] = Bq + (size_t)(bnp * 256 + col_l) * 16384 + (l7 ^ l3) * 8;
  }

  auto issueB = [&](int kt, int buf) {
#pragma unroll
    for (int j = 0; j < 4; ++j) {
      const unsigned short* src = bsrc[j] + kt * 64;
      unsigned short* dst = &Bsb[buf][(w * 32 + j * 8) * 64];
      __builtin_amdgcn_global_load_lds(
          (const __attribute__((address_space(1))) unsigned int*)src,
          (__attribute__((address_space(3))) unsigned int*)dst, 16, 0, 0);
    }
  };
  auto chebpack = [&](float2 cs, unsigned* pk) {
    const float c1 = cs.x, s1 = cs.y, tc = 2.f * c1;
    float cp = c1, sp = s1;
    float cq = tc * c1 - 1.f, sq = tc * s1;
    pk[0] = packbf2(c1, s1);
    pk[1] = packbf2(cq, sq);
#pragma unroll
    for (int g = 2; g < 8; ++g) {
      const float cn = tc * cq - cp, sn = tc * sq - sp;
      pk[g] = packbf2(cn, sn);
      cp = cq; sp = sq; cq = cn; sq = sn;
    }
  };
  auto writeA = [&](int buf, const unsigned* k0) {
    *(u32x4*)(&Asb[buf][row0 * 64 + e0]) = u32x4{k0[0], k0[1], k0[2], k0[3]};
    *(u32x4*)(&Asb[buf][row0 * 64 + (e0 ^ 8)]) = u32x4{k0[4], k0[5], k0[6], k0[7]};
  };

  f32x4 acc[4][4];
#pragma unroll
  for (int m = 0; m < 4; ++m)
#pragma unroll
    for (int n = 0; n < 4; ++n) acc[m][n] = f32x4{0.f, 0.f, 0.f, 0.f};

  // prologue
  unsigned k0[8];
  {
    chebpack(*(const float2*)a2p0, k0);
    writeA(0, k0);
    issueB(0, 0);
  }
  float2 avA = *(const float2*)(a2p0 + 8);  // kt=1
  __syncthreads();

  int buf = 0;
  for (int kt = 0; kt < KT; ++kt) {
    const int nb = buf ^ 1;
    if (kt + 1 < KT) issueB(kt + 1, nb);  // flies under MFMA phase
    float2 avB = avA;
    if (kt + 2 < KT) avB = *(const float2*)(a2p0 + (size_t)(kt + 2) * 8);

    // ---- MFMA phase on buf (verified reads + swizzle)
    {
      const int sr = (lane & 7) << 3;
      short8 af[2][4], bf_[2][4];
#pragma unroll
      for (int ks = 0; ks < 2; ++ks) {
        const int koff = (ks * 32 + (lane >> 4) * 8) ^ sr;
#pragma unroll
        for (int m = 0; m < 4; ++m)
          af[ks][m] = *(const short8*)(&Asb[buf][(wm * 64 + m * 16 + (lane & 15)) * 64 + koff]);
#pragma unroll
        for (int n = 0; n < 4; ++n)
          bf_[ks][n] = *(const short8*)(&Bsb[buf][(wn * 64 + n * 16 + (lane & 15)) * 64 + koff]);
      }
#pragma unroll
      for (int ks = 0; ks < 2; ++ks)
#pragma unroll
        for (int m = 0; m < 4; ++m)
#pragma unroll
          for (int n = 0; n < 4; ++n)
            acc[m][n] = __builtin_amdgcn_mfma_f32_16x16x32_bf16(
                af[ks][m], bf_[ks][n], acc[m][n], 0, 0, 0);
    }

    if (kt + 1 < KT) {  // stage next A tile
      chebpack(avA, k0);
      writeA(nb, k0);
    }
    __syncthreads();  // drains gload_lds + ds writes
    avA = avB;
    buf = nb;
  }

  // epilogue: C/D layout col=lane&15, row=(lane>>4)*4+r (m89/m91-verified)
#pragma unroll
  for (int m = 0; m < 4; ++m) {
    const int r0 = bm * 128 + wm * 64 + m * 16 + (lane >> 4) * 4;
#pragma unroll
    for (int n = 0; n < 4; ++n) {
      const int col = bnp * 256 + wn * 64 + n * 16 + (lane & 15);
#pragma unroll
      for (int r = 0; r < 4; ++r)
        Y[(size_t)(r0 + r) * 1024 + col] = acc[m][n][r];
    }
  }
}

// ---------------- fallback: round-5 kernel verbatim ----------------
static __device__ __forceinline__ short8 trig_pack(float xv, int half) {
  float s1, c1;
  __sincosf(xv, &s1, &c1);
  float ca, sa;
  if (half == 0) {
    ca = c1; sa = s1;
  } else {
    const float c2 = c1 * c1 - s1 * s1, s2 = 2.f * s1 * c1;
    const float c4 = c2 * c2 - s2 * s2, s4 = 2.f * s2 * c2;
    ca = c4 * c1 - s4 * s1; sa = s4 * c1 + c4 * s1;
  }
  const float cb = ca * c1 - sa * s1, sb = sa * c1 + ca * s1;
  const float cc = cb * c1 - sb * s1, sc = sb * c1 + cb * s1;
  const float cd = cc * c1 - sc * s1, sd = sc * c1 + cc * s1;
  short8 v;
  v[0] = (short)f2bf_rne(ca); v[1] = (short)f2bf_rne(sa);
  v[2] = (short)f2bf_rne(cb); v[3] = (short)f2bf_rne(sb);
  v[4] = (short)f2bf_rne(cc); v[5] = (short)f2bf_rne(sc);
  v[6] = (short)f2bf_rne(cd); v[7] = (short)f2bf_rne(sd);
  return v;
}
static __device__ __forceinline__ short8 pack_w(float4 w0, float4 w1) {
  short8 v;
  v[0] = (short)f2bf_rne(w0.x); v[1] = (short)f2bf_rne(w1.x);
  v[2] = (short)f2bf_rne(w0.y); v[3] = (short)f2bf_rne(w1.y);
  v[4] = (short)f2bf_rne(w0.z); v[5] = (short)f2bf_rne(w1.z);
  v[6] = (short)f2bf_rne(w0.w); v[7] = (short)f2bf_rne(w1.w);
  return v;
}

__global__ __launch_bounds__(256, 2) void fkan_fallback(
    const float* __restrict__ X, const float* __restrict__ W,
    float* __restrict__ Y) {
  constexpr int N = 1024, KT = 256;
  __shared__ alignas(16) unsigned short Asb[128 * 64];
  __shared__ alignas(16) unsigned short Bsb[128 * 64];
  const int tid = threadIdx.x;
  const int bm = blockIdx.x & 63;
  const int bn = blockIdx.x >> 6;
  const int lane = tid & 63;
  const int w = tid >> 6;
  const int wm = w >> 1, wn = w & 1;
  const float* W0 = W;
  const float* W1 = W + 8388608;
  const int rowbase = tid >> 3;
  const int il = (tid & 7) >> 1;
  const int half = tid & 1;
  const int sst = (rowbase & 7) << 3;
  const int aoff0 = rowbase * 64 + ((il * 16 + half * 8) ^ sst);
  const size_t xaddr0 = (size_t)(bm * 128 + rowbase) * 1024 + il;
  const size_t wbase0 = (size_t)(bn * 128 + rowbase) * 8192 + il * 8 + half * 4;

  f32x4 acc[4][4];
#pragma unroll
  for (int m = 0; m < 4; ++m)
#pragma unroll
    for (int n = 0; n < 4; ++n) acc[m][n] = f32x4{0.f, 0.f, 0.f, 0.f};

  float xq[4];
  float4 wq0[4], wq1[4];
#pragma unroll
  for (int p = 0; p < 4; ++p) {
    xq[p] = X[xaddr0 + p * 32768];
    wq0[p] = *(const float4*)(W0 + wbase0 + p * 262144);
    wq1[p] = *(const float4*)(W1 + wbase0 + p * 262144);
  }

  for (int kt = 0; kt < KT; ++kt) {
    short8 va[4], vb[4];
#pragma unroll
    for (int p = 0; p < 4; ++p) {
      va[p] = trig_pack(xq[p], half);
      vb[p] = pack_w(wq0[p], wq1[p]);
    }
    __syncthreads();
#pragma unroll
    for (int p = 0; p < 4; ++p) {
      *(short8*)(Asb + aoff0 + p * 2048) = va[p];
      *(short8*)(Bsb + aoff0 + p * 2048) = vb[p];
    }
    const int ktn = (kt < KT - 1) ? kt + 1 : kt;
    const size_t xo = xaddr0 + (size_t)ktn * 4;
    const size_t wo = wbase0 + (size_t)ktn * 32;
#pragma unroll
    for (int p = 0; p < 4; ++p) {
      xq[p] = X[xo + p * 32768];
      wq0[p] = *(const float4*)(W0 + wo + p * 262144);
      wq1[p] = *(const float4*)(W1 + wo + p * 262144);
    }
    __syncthreads();
    const int sr = (lane & 7) << 3;
    short8 af[2][4], bf_[2][4];
#pragma unroll
    for (int ks = 0; ks < 2; ++ks) {
      const int koff = ks * 32 + (lane >> 4) * 8;
#pragma unroll
      for (int m = 0; m < 4; ++m)
        af[ks][m] = *(const short8*)(Asb + (wm * 64 + m * 16 + (lane & 15)) * 64 + (koff ^ sr));
#pragma unroll
      for (int n = 0; n < 4; ++n)
        bf_[ks][n] = *(const short8*)(Bsb + (wn * 64 + n * 16 + (lane & 15)) * 64 + (koff ^ sr));
    }
#pragma unroll
    for (int ks = 0; ks < 2; ++ks)
#pragma unroll
      for (int m = 0; m < 4; ++m)
#pragma unroll
        for (int n = 0; n < 4; ++n)
          acc[m][n] = __builtin_amdgcn_mfma_f32_16x16x32_bf16(
              af[ks][m], bf_[ks][n], acc[m][n], 0, 0, 0);
  }
#pragma unroll
  for (int m = 0; m < 4; ++m) {
    const int r0 = bm * 128 + wm * 64 + m * 16 + (lane >> 4) * 4;
#pragma unroll
    for (int n = 0; n < 4; ++n) {
      const int col = bn * 128 + wn * 64 + n * 16 + (lane & 15);
#pragma unroll
      for (int r = 0; r < 4; ++r)
        Y[(size_t)(r0 + r) * N + col] = acc[m][n][r];
    }
  }
}

extern "C" void kernel_launch(void* const* d_in, const int* in_sizes, int n_in,
                              void* d_out, int out_size, void* d_ws, size_t ws_size,
                              hipStream_t stream) {
  const float* x = (const float*)d_in[0];
  const float* w = (const float*)d_in[1];
  float* y = (float*)d_out;
  constexpr size_t A2_BYTES = 67108864ull;   // 64 MB sincos f32
  constexpr size_t BQ_BYTES = 33554432ull;   // 32 MB bf16 W
  if (ws_size >= A2_BYTES + BQ_BYTES) {
    float* a2 = (float*)d_ws;
    unsigned short* bq = (unsigned short*)((char*)d_ws + A2_BYTES);
    fkan_pre_a<<<dim3(8192), dim3(256), 0, stream>>>(x, a2);
    fkan_pre_b<<<dim3(4096), dim3(256), 0, stream>>>(w, bq);
    fkan_main<<<dim3(256), dim3(512), 0, stream>>>(a2, bq, y);
  } else {
    fkan_fallback<<<dim3(512), dim3(256), 0, stream>>>(x, w, y);
  }
}